// Round 2
// baseline (322.456 us; speedup 1.0000x reference)
//
#include <hip/hip_runtime.h>

#define B_ 16
#define T_ 2048
#define NK 64
#define NH 128

// One kernel. Block = 512 threads = 8 waves; block owns 64 consecutive t-rows
// (lane = t within tile); the 8 waves split the s-range into 8 contiguous
// chunks processed in descending s with per-lane suffix accumulation.
// Chunk composability: delta = local_suffix + (sum of sims in higher chunks),
// so w = sim*exp(-lam*local)*exp(-lam*Roff) and partial (num,den,total)
// combine exactly in the epilogue.
__global__ __launch_bounds__(512) void emam_main(
    const float* __restrict__ y,
    const int*   __restrict__ pseq,
    const float* __restrict__ A,
    const float* __restrict__ kcw,
    const float* __restrict__ lam_w,   const float* __restrict__ lam_b,
    const float* __restrict__ guess_w, const float* __restrict__ guess_b,
    const float* __restrict__ slip_w,  const float* __restrict__ slip_b,
    float* __restrict__ out)
{
  __shared__ float wvec[3][NK];    // W @ {lam_w, guess_w, slip_w}
  __shared__ float sh[3][8][64];   // per-wave partials: num, den, chunk-total

  // Fold kc out: wvec[v][k] = sum_h kcw[k,h] * w_v[h]
  int j = threadIdx.x;
  if (j < 3*NK) {
    int vec = j >> 6, k = j & 63;
    const float* wv = (vec==0) ? lam_w : (vec==1 ? guess_w : slip_w);
    float acc = 0.f;
    #pragma unroll 8
    for (int h = 0; h < NH; ++h) acc = fmaf(kcw[k*NH + h], wv[h], acc);
    wvec[vec][k] = acc;
  }
  __syncthreads();

  const int bid  = blockIdx.x;
  const int b    = bid >> 5;
  const int tile = 31 - (bid & 31);          // heavy tiles first (load balance)
  const int t0   = tile << 6;
  const int lane = threadIdx.x & 63;
  const int wid  = __builtin_amdgcn_readfirstlane(threadIdx.x >> 6); // force SGPR
  const int t    = t0 + lane;
  const int base = b * T_;

  // Gather x_t = A[pseq[b,t]] into registers (per-lane, 64 VGPRs)
  const int pt = pseq[base + t];
  const float* xr = A + ((size_t)pt << 6);
  float xt[NK];
  #pragma unroll
  for (int k = 0; k < NK; k += 4) {
    float4 v = *reinterpret_cast<const float4*>(xr + k);
    xt[k] = v.x; xt[k+1] = v.y; xt[k+2] = v.z; xt[k+3] = v.w;
  }

  // lam_t = exp(x_t . wl + lam_b)
  float accL = 0.f;
  #pragma unroll
  for (int k = 0; k < NK; ++k) accL = fmaf(xt[k], wvec[0][k], accL);
  const float lam_t = __expf(accL + lam_b[0]);
  const float nlam  = -lam_t;

  // s-range [0, L) split into 8 contiguous chunks, one per wave.
  const int L  = t0 + 63;          // max s needed = t0+62 (strictly past)
  const int C  = (L + 7) >> 3;
  const int lo = wid * C;
  const int hi = min(lo + C, L);

  float R = 0.f, num = 0.f, den = 0.f;
  for (int s = hi - 1; s >= lo; --s) {
    const int p = pseq[base + s];               // wave-uniform -> s_load
    const float* xs = A + ((size_t)p << 6);     // wave-uniform row
    float a0 = 0.f, a1 = 0.f, a2 = 0.f, a3 = 0.f;
    #pragma unroll
    for (int k = 0; k < NK; k += 4) {
      a0 = fmaf(xs[k  ], xt[k  ], a0);
      a1 = fmaf(xs[k+1], xt[k+1], a1);
      a2 = fmaf(xs[k+2], xt[k+2], a2);
      a3 = fmaf(xs[k+3], xt[k+3], a3);
    }
    float sim = (a0 + a1) + (a2 + a3);
    sim = (s < t) ? sim : 0.f;                  // strictly-past mask
    R += sim;                                   // suffix sum incl. s
    const float wgt = sim * __expf(nlam * R);
    num = fmaf(y[base + s], wgt, num);
    den += wgt;
  }

  sh[0][wid][lane] = num;
  sh[1][wid][lane] = den;
  sh[2][wid][lane] = R;
  __syncthreads();

  // Wave 0: combine the 8 chunks (descending s), epilogue, store.
  if (threadIdx.x < 64) {
    float Roff = 0.f, N = 0.f, D = 0.f;
    #pragma unroll
    for (int ww = 7; ww >= 0; --ww) {
      const float e = __expf(nlam * Roff);
      N = fmaf(sh[0][ww][lane], e, N);
      D = fmaf(sh[1][ww][lane], e, D);
      Roff += sh[2][ww][lane];
    }
    float accG = 0.f, accS = 0.f;
    #pragma unroll
    for (int k = 0; k < NK; ++k) {
      accG = fmaf(xt[k], wvec[1][k], accG);
      accS = fmaf(xt[k], wvec[2][k], accS);
    }
    const float g  = 1.f / (1.f + __expf(-(accG + guess_b[0])));
    const float sl = 1.f / (1.f + __expf(-(accS + slip_b[0])));
    const float h  = N / (D + 1e-6f);
    float yh = h * (1.f - sl) + (1.f - h) * g;
    yh = fminf(fmaxf(yh, 0.01f), 0.99f);
    out[base + t] = yh;
  }
}

extern "C" void kernel_launch(void* const* d_in, const int* in_sizes, int n_in,
                              void* d_out, int out_size, void* d_ws, size_t ws_size,
                              hipStream_t stream) {
  const float* y    = (const float*)d_in[0];
  const int*   pseq = (const int*)  d_in[1];
  const float* A    = (const float*)d_in[2];
  const float* kcw  = (const float*)d_in[3];
  const float* lw   = (const float*)d_in[4];
  const float* lb   = (const float*)d_in[5];
  const float* gw   = (const float*)d_in[6];
  const float* gb   = (const float*)d_in[7];
  const float* sw   = (const float*)d_in[8];
  const float* sb   = (const float*)d_in[9];
  float* out = (float*)d_out;

  dim3 grid(B_ * (T_ / 64));   // 512 blocks
  dim3 block(512);             // 8 waves: 8-way s-chunk split per t-tile
  emam_main<<<grid, block, 0, stream>>>(y, pseq, A, kcw, lw, lb, gw, gb, sw, sb, out);
}

// Round 3
// 183.538 us; speedup vs baseline: 1.7569x; 1.7569x over previous
//
#include <hip/hip_runtime.h>

#define B_ 16
#define T_ 2048
#define NK 64
#define NH 128
#define ITEMS_PER_B 528            /* sum_{tile=0}^{31} (tile+1) */
#define N_ITEMS (B_ * ITEMS_PER_B) /* 8448 equal-size wave work-items */
#define WS_WVEC 0                  /* 3*64 floats: kcw @ {lam_w,guess_w,slip_w} */
#define WS_PART 256                /* float offset where per-item partials start */

// ---------------- prep: fold kc out -> wvec[3][64] in workspace ----------------
__global__ __launch_bounds__(256) void prep_kernel(
    const float* __restrict__ kcw, const float* __restrict__ lam_w,
    const float* __restrict__ guess_w, const float* __restrict__ slip_w,
    float* __restrict__ ws) {
  int j = threadIdx.x;
  if (j < 3 * NK) {
    int vec = j >> 6, k = j & 63;
    const float* wv = (vec == 0) ? lam_w : (vec == 1 ? guess_w : slip_w);
    float acc = 0.f;
    #pragma unroll 8
    for (int h = 0; h < NH; ++h) acc = fmaf(kcw[k * NH + h], wv[h], acc);
    ws[WS_WVEC + vec * NK + k] = acc;
  }
}

// ---------------- phase 1: equal-size wave items, LDS-staged inner loop --------
// Item = (b, tile, chunk): 64 t-lanes (t = tile*64+lane), s in [chunk*64, chunk*64+64)
// clipped to [0, tile*64+63). Partials (num, den, chunk-total) -> ws.
// Chunk factorization: delta(s) = R_local(s) + sum(totals of higher chunks), exact.
__global__ __launch_bounds__(256, 4) void phase1(
    const float* __restrict__ y, const int* __restrict__ pseq,
    const float* __restrict__ A, const float* __restrict__ lam_b,
    float* __restrict__ ws) {
  __shared__ float xs[4][16][68];   // per-wave staging, padded row (68 floats)
  __shared__ float yl[4][16];

  const int lane = threadIdx.x & 63;
  const int wv   = __builtin_amdgcn_readfirstlane(threadIdx.x >> 6);
  const int item = blockIdx.x * 4 + wv;

  // decode item -> (b, tile, chunk)  (all wave-uniform)
  const int b = item / ITEMS_PER_B;
  const int r = item - b * ITEMS_PER_B;
  int tile = (int)((sqrtf(8.f * (float)r + 1.f) - 1.f) * 0.5f);
  while ((tile + 1) * (tile + 2) / 2 <= r) ++tile;
  while (tile * (tile + 1) / 2 > r) --tile;
  const int chunk = r - tile * (tile + 1) / 2;

  const int t0   = tile << 6;
  const int base = b * T_;
  const int t    = t0 + lane;

  // x_t gather into registers
  const float* xr = A + ((size_t)pseq[base + t] << 6);
  float xt[NK];
  #pragma unroll
  for (int k = 0; k < NK; k += 4) {
    float4 v = *reinterpret_cast<const float4*>(xr + k);
    xt[k] = v.x; xt[k + 1] = v.y; xt[k + 2] = v.z; xt[k + 3] = v.w;
  }

  // lam_t (wvec0 loads are uniform -> scalar)
  float accL = 0.f;
  #pragma unroll
  for (int k = 0; k < NK; ++k) accL = fmaf(xt[k], ws[WS_WVEC + k], accL);
  const float nlam = -__expf(accL + lam_b[0]);

  const int s0   = chunk << 6;
  const int send = min(s0 + 64, t0 + 63);   // strictly-past bound

  float R = 0.f, num = 0.f, den = 0.f;
  for (int sub = 3; sub >= 0; --sub) {      // descending s, 16 rows per stage
    const int sbase = s0 + (sub << 4);
    // ---- stage 16 rows (4 lanes per row, 16 floats each, coalesced x4 loads)
    const int row  = lane >> 2;
    const int sidx = sbase + row;
    const bool ok  = sidx < send;
    float4 v0 = {0,0,0,0}, v1 = {0,0,0,0}, v2 = {0,0,0,0}, v3 = {0,0,0,0};
    if (ok) {
      const float* src = A + ((size_t)pseq[base + sidx] << 6) + ((lane & 3) << 4);
      v0 = *reinterpret_cast<const float4*>(src);
      v1 = *reinterpret_cast<const float4*>(src + 4);
      v2 = *reinterpret_cast<const float4*>(src + 8);
      v3 = *reinterpret_cast<const float4*>(src + 12);
    }
    float* dst = &xs[wv][row][(lane & 3) << 4];
    reinterpret_cast<float4*>(dst)[0] = v0;
    reinterpret_cast<float4*>(dst)[1] = v1;
    reinterpret_cast<float4*>(dst)[2] = v2;
    reinterpret_cast<float4*>(dst)[3] = v3;
    if (lane < 16)
      yl[wv][lane] = (sbase + lane < send) ? y[base + sbase + lane] : 0.f;
    // (same-wave LDS RAW: compiler inserts lgkmcnt waits; no barrier needed)

    // ---- consume 16 rows, descending s
    for (int i = 15; i >= 0; --i) {
      const int s = sbase + i;
      const float4* rowp = reinterpret_cast<const float4*>(&xs[wv][i][0]);
      float a0 = 0.f, a1 = 0.f, a2 = 0.f, a3 = 0.f;
      #pragma unroll
      for (int q = 0; q < 16; ++q) {
        float4 xv = rowp[q];            // broadcast ds_read_b128
        a0 = fmaf(xv.x, xt[4 * q    ], a0);
        a1 = fmaf(xv.y, xt[4 * q + 1], a1);
        a2 = fmaf(xv.z, xt[4 * q + 2], a2);
        a3 = fmaf(xv.w, xt[4 * q + 3], a3);
      }
      float sim = (a0 + a1) + (a2 + a3);
      sim = (s < t) ? sim : 0.f;        // strictly-past mask
      R += sim;
      const float w = sim * __expf(nlam * R);
      num = fmaf(yl[wv][i], w, num);
      den += w;
    }
  }

  float* po = ws + WS_PART + (size_t)item * 192;
  po[lane] = num; po[64 + lane] = den; po[128 + lane] = R;
}

// ---------------- phase 2: combine chunks (descending), epilogue, store --------
__global__ __launch_bounds__(64) void phase2(
    const int* __restrict__ pseq, const float* __restrict__ A,
    const float* __restrict__ ws, const float* __restrict__ lam_b,
    const float* __restrict__ guess_b, const float* __restrict__ slip_b,
    float* __restrict__ out) {
  const int bid = blockIdx.x;        // b*32 + tile
  const int b = bid >> 5, tile = bid & 31;
  const int lane = threadIdx.x;
  const int t = (tile << 6) + lane;
  const int base = b * T_;

  const float* xr = A + ((size_t)pseq[base + t] << 6);
  float xt[NK];
  #pragma unroll
  for (int k = 0; k < NK; k += 4) {
    float4 v = *reinterpret_cast<const float4*>(xr + k);
    xt[k] = v.x; xt[k + 1] = v.y; xt[k + 2] = v.z; xt[k + 3] = v.w;
  }
  float aL = 0.f, aG = 0.f, aS = 0.f;
  #pragma unroll
  for (int k = 0; k < NK; ++k) {
    aL = fmaf(xt[k], ws[WS_WVEC + k], aL);          // same order as phase1
    aG = fmaf(xt[k], ws[WS_WVEC + 64 + k], aG);
    aS = fmaf(xt[k], ws[WS_WVEC + 128 + k], aS);
  }
  const float nlam = -__expf(aL + lam_b[0]);

  float N = 0.f, D = 0.f, Roff = 0.f;
  const int ibase = b * ITEMS_PER_B + tile * (tile + 1) / 2;
  for (int c = tile; c >= 0; --c) {                 // descending s
    const float* p = ws + WS_PART + (size_t)(ibase + c) * 192;
    const float e = __expf(nlam * Roff);
    N = fmaf(p[lane], e, N);
    D = fmaf(p[64 + lane], e, D);
    Roff += p[128 + lane];
  }
  const float g  = 1.f / (1.f + __expf(-(aG + guess_b[0])));
  const float sl = 1.f / (1.f + __expf(-(aS + slip_b[0])));
  const float h  = N / (D + 1e-6f);
  float yh = h * (1.f - sl) + (1.f - h) * g;
  out[base + t] = fminf(fmaxf(yh, 0.01f), 0.99f);
}

extern "C" void kernel_launch(void* const* d_in, const int* in_sizes, int n_in,
                              void* d_out, int out_size, void* d_ws, size_t ws_size,
                              hipStream_t stream) {
  const float* y    = (const float*)d_in[0];
  const int*   pseq = (const int*)  d_in[1];
  const float* A    = (const float*)d_in[2];
  const float* kcw  = (const float*)d_in[3];
  const float* lw   = (const float*)d_in[4];
  const float* lb   = (const float*)d_in[5];
  const float* gw   = (const float*)d_in[6];
  const float* gb   = (const float*)d_in[7];
  const float* sw   = (const float*)d_in[8];
  const float* sb   = (const float*)d_in[9];
  float* out = (float*)d_out;
  float* ws  = (float*)d_ws;   // needs (256 + 8448*192)*4 B ~= 6.5 MB

  prep_kernel<<<1, 256, 0, stream>>>(kcw, lw, gw, sw, ws);
  phase1<<<N_ITEMS / 4, 256, 0, stream>>>(y, pseq, A, lb, ws);
  phase2<<<B_ * 32, 64, 0, stream>>>(pseq, A, ws, lb, gb, sb, out);
}